// Round 4
// baseline (1021.442 us; speedup 1.0000x reference)
//
#include <hip/hip_runtime.h>

// (B,N,D,L) = (32,1000,256,3), all fp32.
// d_in: [0]=x (unused), [1]=node_feature, [2]=Ws (L,D,D), [3]=bs (L,D).
// Math collapses (A_norm = ones/N):
//   h[b,:] = MLP(mean_n nf[b,n,:]);  out0 = nf + h (broadcast);  out1 = nf.
//
// R3 post-mortem: container died; the only audit finding was the
// poison-value-dependent counter init (stale ctr across un-poisoned replays
// => all 1600 blocks spin out their guard). R4 removes the poison dependence:
// a 2us k_init zeroes ctr/flag every launch (graph-replayed), winner condition
// is oldv == SS-1. Everything else keeps the R3 plan: ONE data kernel, nf read
// from HBM exactly once, held in registers across a per-batch last-arriver
// sync; the 50th block of each b runs the 3-layer MLP and releases a flag;
// the other 49 spin (t0-only, s_sleep, bounded) then write out0 from regs.
#define BB 32
#define NN 1000
#define DD 256
#define SS 50                   // chunks per batch; SS*RPS == NN
#define RPS 20                  // rows per chunk
#define ELEMS (BB * NN * DD)    // 8,192,000 floats per output tensor

// ---- K0: zero the 32 counters + 32 flags (64 words). Replayed per-iter. ----
__global__ __launch_bounds__(64) void k_init(unsigned* __restrict__ sync) {
    sync[threadIdx.x] = 0u;
}

__global__ __launch_bounds__(256, 7) void k_all(const float4* __restrict__ nf4,
                                                const float* __restrict__ Ws,
                                                const float* __restrict__ bsv,
                                                float4* __restrict__ out0_4,
                                                float4* __restrict__ out1_4,
                                                float* __restrict__ partials,
                                                float* __restrict__ hws,
                                                unsigned* __restrict__ ctr,
                                                unsigned* __restrict__ flag) {
    const int s = blockIdx.x, b = blockIdx.y, t = threadIdx.x;
    const int r4 = t >> 6, c = t & 63;

    __shared__ __align__(16) float red[1024];
    __shared__ __align__(16) float h[2][DD];
    __shared__ __align__(16) float hsh[DD];
    __shared__ unsigned oldv;

    // ---- Phase A: nf -> regs, out1 = nf, partial column sums ----
    float4 vv[5];
    float ax = 0.f, ay = 0.f, az = 0.f, aw = 0.f;
#pragma unroll
    for (int i = 0; i < 5; i++) {
        const int n = s * RPS + i * 4 + r4;
        const int idx = (b * NN + n) * (DD / 4) + c;
        float4 v = nf4[idx];
        vv[i] = v;
        out1_4[idx] = v;                       // output 1 (= nf), same pass
        ax += v.x; ay += v.y; az += v.z; aw += v.w;
    }
    ((float4*)red)[r4 * 64 + c] = make_float4(ax, ay, az, aw);
    __syncthreads();
    const float sum = red[t] + red[256 + t] + red[512 + t] + red[768 + t];
    // relaxed agent-scope stores; ordering provided by the ACQ_REL RMW below
    __hip_atomic_store(&partials[(b * SS + s) * DD + t], sum,
                       __ATOMIC_RELAXED, __HIP_MEMORY_SCOPE_AGENT);
    __syncthreads();                           // all 256 stores issued+complete
    if (t == 0)
        oldv = __hip_atomic_fetch_add(&ctr[b], 1u,
                                      __ATOMIC_ACQ_REL, __HIP_MEMORY_SCOPE_AGENT);
    __syncthreads();

    // ---- Phase B (last arriver of this b only): 3-layer MLP on the mean ----
    if (oldv == (unsigned)(SS - 1)) {
        float acc = 0.f;
#pragma unroll 10
        for (int sp = 0; sp < SS; sp++)
            acc += __hip_atomic_load(&partials[(b * SS + sp) * DD + t],
                                     __ATOMIC_RELAXED, __HIP_MEMORY_SCOPE_AGENT);
        h[0][t] = acc * (1.0f / (float)NN);
        __syncthreads();
        int cur = 0;
        for (int l = 0; l < 3; l++) {
            const float* __restrict__ W = Ws + l * DD * DD;
            float a = 0.f;
#pragma unroll 8
            for (int k = 0; k < DD; k++)
                a = fmaf(h[cur][k], W[k * DD + t], a);  // h: LDS broadcast; W coalesced
            a += bsv[l * DD + t];
            if (l < 2) a = fmaxf(a, 0.f);
            h[cur ^ 1][t] = a;                 // double buffer: no WAR on h[cur]
            cur ^= 1;
            __syncthreads();
        }
        __hip_atomic_store(&hws[b * DD + t], h[cur][t],
                           __ATOMIC_RELAXED, __HIP_MEMORY_SCOPE_AGENT);
        __syncthreads();                       // hws stores done before flag
        if (t == 0)
            __hip_atomic_store(&flag[b], 1u,
                               __ATOMIC_RELEASE, __HIP_MEMORY_SCOPE_AGENT);
    }

    // ---- wait for this b's h (winner sees its own flag immediately) ----
    if (t == 0) {
        int guard = 100000;                    // ~20ms bound; never hit if correct
        while (__hip_atomic_load(&flag[b], __ATOMIC_ACQUIRE,
                                 __HIP_MEMORY_SCOPE_AGENT) != 1u) {
            if (--guard == 0) break;
            __builtin_amdgcn_s_sleep(8);
        }
    }
    __syncthreads();
    hsh[t] = __hip_atomic_load(&hws[b * DD + t],
                               __ATOMIC_RELAXED, __HIP_MEMORY_SCOPE_AGENT);
    __syncthreads();
    const float4 hv = ((const float4*)hsh)[c];

    // ---- Phase C: out0 = regs + h[b]; zero nf re-read ----
#pragma unroll
    for (int i = 0; i < 5; i++) {
        const int n = s * RPS + i * 4 + r4;
        const int idx = (b * NN + n) * (DD / 4) + c;
        float4 v = vv[i];
        out0_4[idx] = make_float4(v.x + hv.x, v.y + hv.y, v.z + hv.z, v.w + hv.w);
    }
}

extern "C" void kernel_launch(void* const* d_in, const int* in_sizes, int n_in,
                              void* d_out, int out_size, void* d_ws, size_t ws_size,
                              hipStream_t stream) {
    const float4* nf4 = (const float4*)d_in[1];  // node_feature
    const float* Ws   = (const float*)d_in[2];   // (L,D,D)
    const float* bsv  = (const float*)d_in[3];   // (L,D)
    float4* out0 = (float4*)d_out;
    float4* out1 = (float4*)((float*)d_out + ELEMS);

    float* partials = (float*)d_ws;                // SS*BB*DD floats (1.6 MB)
    float* hws      = partials + SS * BB * DD;     // BB*DD floats (32 KB)
    unsigned* sync  = (unsigned*)(hws + BB * DD);  // 64 words: ctr[32] | flag[32]
    unsigned* ctr   = sync;
    unsigned* flag  = sync + BB;

    k_init<<<1, 64, 0, stream>>>(sync);
    k_all<<<dim3(SS, BB), 256, 0, stream>>>(nf4, Ws, bsv, out0, out1,
                                            partials, hws, ctr, flag);
}

// Round 5
// 163.333 us; speedup vs baseline: 6.2537x; 6.2537x over previous
//
#include <hip/hip_runtime.h>

// (B,N,D,L) = (32,1000,256,3), all fp32.
// d_in: [0]=x (unused), [1]=node_feature, [2]=Ws (L,D,D), [3]=bs (L,D).
// Math collapses (A_norm = ones/N):
//   h[b,:] = MLP(mean_n nf[b,n,:]);  out0 = nf + h (broadcast);  out1 = nf.
//
// R4 post-mortem: k_all=1021us, VALUBusy 0.12%, traffic normal => the machine
// WAITED. Cause: ACQUIRE atomic polls emit buffer_inv (full XCD-L2 invalidate)
// per poll; 1550 spinners => cache-maintenance storm. R5: ALL cross-block
// atomics are RELAXED agent-scope (plain sc1 write-through ops, coherent at
// the fabric, ZERO buffer_inv/wbl2). Required ordering comes from hardware
// drains instead of fences:
//   - __syncthreads() emits s_waitcnt vmcnt(0) before s_barrier, so partials
//     sc1-stores are at the coherence point before t0's ctr RMW issues, and
//     hws sc1-stores are at the coherence point before the flag store issues.
//   - consumers observe flag, cross a barrier, then issue sc1 loads (cannot
//     be hoisted above an atomic-observed branch + barrier).
#define BB 32
#define NN 1000
#define DD 256
#define SS 50                   // chunks per batch; SS*RPS == NN
#define RPS 20                  // rows per chunk
#define ELEMS (BB * NN * DD)    // 8,192,000 floats per output tensor

#define LD_A(p)     __hip_atomic_load((p),      __ATOMIC_RELAXED, __HIP_MEMORY_SCOPE_AGENT)
#define ST_A(p, v)  __hip_atomic_store((p), (v), __ATOMIC_RELAXED, __HIP_MEMORY_SCOPE_AGENT)

// ---- K0: zero the 32 counters + 32 flags (64 words). Replayed per-iter. ----
__global__ __launch_bounds__(64) void k_init(unsigned* __restrict__ sync) {
    sync[threadIdx.x] = 0u;
}

__global__ __launch_bounds__(256, 7) void k_all(const float4* __restrict__ nf4,
                                                const float* __restrict__ Ws,
                                                const float* __restrict__ bsv,
                                                float4* __restrict__ out0_4,
                                                float4* __restrict__ out1_4,
                                                float* __restrict__ partials,
                                                float* __restrict__ hws,
                                                unsigned* __restrict__ ctr,
                                                unsigned* __restrict__ flag) {
    const int s = blockIdx.x, b = blockIdx.y, t = threadIdx.x;
    const int r4 = t >> 6, c = t & 63;

    __shared__ __align__(16) float red[1024];
    __shared__ __align__(16) float h[2][DD];
    __shared__ __align__(16) float hsh[DD];
    __shared__ unsigned oldv;

    // ---- Phase A: nf -> regs, out1 = nf, partial column sums ----
    float4 vv[5];
    float ax = 0.f, ay = 0.f, az = 0.f, aw = 0.f;
#pragma unroll
    for (int i = 0; i < 5; i++) {
        const int n = s * RPS + i * 4 + r4;
        const int idx = (b * NN + n) * (DD / 4) + c;
        float4 v = nf4[idx];
        vv[i] = v;
        out1_4[idx] = v;                       // output 1 (= nf), same pass
        ax += v.x; ay += v.y; az += v.z; aw += v.w;
    }
    ((float4*)red)[r4 * 64 + c] = make_float4(ax, ay, az, aw);
    __syncthreads();
    const float sum = red[t] + red[256 + t] + red[512 + t] + red[768 + t];
    ST_A(&partials[(b * SS + s) * DD + t], sum);   // sc1 write-through
    __syncthreads();                           // vmcnt(0): stores at coherence pt
    if (t == 0)
        oldv = __hip_atomic_fetch_add(&ctr[b], 1u,
                                      __ATOMIC_RELAXED, __HIP_MEMORY_SCOPE_AGENT);
    __syncthreads();

    // ---- Phase B (last arriver of this b only): 3-layer MLP on the mean ----
    if (oldv == (unsigned)(SS - 1)) {
        float acc = 0.f;
#pragma unroll 10
        for (int sp = 0; sp < SS; sp++)
            acc += LD_A(&partials[(b * SS + sp) * DD + t]);
        h[0][t] = acc * (1.0f / (float)NN);
        __syncthreads();
        int cur = 0;
        for (int l = 0; l < 3; l++) {
            const float* __restrict__ W = Ws + l * DD * DD;
            float a = 0.f;
#pragma unroll 16
            for (int k = 0; k < DD; k++)
                a = fmaf(h[cur][k], W[k * DD + t], a);  // h: LDS bcast; W coalesced
            a += bsv[l * DD + t];
            if (l < 2) a = fmaxf(a, 0.f);
            h[cur ^ 1][t] = a;                 // double buffer: no WAR on h[cur]
            cur ^= 1;
            __syncthreads();
        }
        ST_A(&hws[b * DD + t], h[cur][t]);     // sc1 write-through
        __syncthreads();                       // vmcnt(0): hws at coherence pt
        if (t == 0)
            ST_A(&flag[b], 1u);
    }

    // ---- wait for this b's h (winner sees its own flag immediately) ----
    if (t == 0) {
        int guard = 20000;                     // ~17ms bound; never hit if correct
        while (LD_A(&flag[b]) != 1u) {         // relaxed poll: NO buffer_inv
            if (--guard == 0) break;
            __builtin_amdgcn_s_sleep(32);      // ~0.85us backoff
        }
    }
    __syncthreads();
    hsh[t] = LD_A(&hws[b * DD + t]);           // sc1 load: coherent, post-flag
    __syncthreads();
    const float4 hv = ((const float4*)hsh)[c];

    // ---- Phase C: out0 = regs + h[b]; zero nf re-read ----
#pragma unroll
    for (int i = 0; i < 5; i++) {
        const int n = s * RPS + i * 4 + r4;
        const int idx = (b * NN + n) * (DD / 4) + c;
        float4 v = vv[i];
        out0_4[idx] = make_float4(v.x + hv.x, v.y + hv.y, v.z + hv.z, v.w + hv.w);
    }
}

extern "C" void kernel_launch(void* const* d_in, const int* in_sizes, int n_in,
                              void* d_out, int out_size, void* d_ws, size_t ws_size,
                              hipStream_t stream) {
    const float4* nf4 = (const float4*)d_in[1];  // node_feature
    const float* Ws   = (const float*)d_in[2];   // (L,D,D)
    const float* bsv  = (const float*)d_in[3];   // (L,D)
    float4* out0 = (float4*)d_out;
    float4* out1 = (float4*)((float*)d_out + ELEMS);

    float* partials = (float*)d_ws;                // SS*BB*DD floats (1.6 MB)
    float* hws      = partials + SS * BB * DD;     // BB*DD floats (32 KB)
    unsigned* sync  = (unsigned*)(hws + BB * DD);  // 64 words: ctr[32] | flag[32]
    unsigned* ctr   = sync;
    unsigned* flag  = sync + BB;

    k_init<<<1, 64, 0, stream>>>(sync);
    k_all<<<dim3(SS, BB), 256, 0, stream>>>(nf4, Ws, bsv, out0, out1,
                                            partials, hws, ctr, flag);
}